// Round 10
// baseline (1192.403 us; speedup 1.0000x reference)
//
#include <hip/hip_runtime.h>
#include <math.h>

// ---------------- problem constants (fixed inputs: key 0) ----------------
#define BN 16384
#define DN 1024

// ---------------- workspace layout (bytes, all 256-aligned) ----------------
static constexpr size_t OFF_C    = 0x000000;  // f32 [1024*1024]  G -> Chat -> M4  [ZERO]
static constexpr size_t OFF_P    = 0x400000;  // f32 [1024*1024]  M2 (T4) then mv partials
static constexpr size_t OFF_Y0   = 0x800000;  // f32 [64][1024]
static constexpr size_t OFF_Y1   = 0x840000;
static constexpr size_t OFF_Y2   = 0x880000;
static constexpr size_t OFF_Y3   = 0x8C0000;
static constexpr size_t OFF_CQ   = 0x900000;  // f32 [64][1024]
static constexpr size_t OFF_S64  = 0x940000;  // f64 [64*64] gram
static constexpr size_t OFF_LF   = 0x948000;  // (unused now)
static constexpr size_t OFF_T64  = 0x950000;  // f64 [64*64] RR matrix (in M-space)
static constexpr size_t OFF_V16  = 0x958000;  // f32 [64*16] top-16 eigvecs
static constexpr size_t OFF_UT   = 0x960000;  // f32 [16][1024]
static constexpr size_t OFF_UTT  = 0x970000;  // f32 [1024][16]
static constexpr size_t OFF_S16  = 0x980000;  // f32 [16]
static constexpr size_t OFF_CS   = 0x980100;  // f32 [1024] colsum           [ZERO]
static constexpr size_t OFF_TR   = 0x981100;  // f32 [1] trace               [ZERO]
static constexpr size_t OFF_SCAL = 0x981200;  // f32 [2] mid, inv_e
static constexpr size_t OFF_STAT = 0x981300;  // f32 [10*153] stats          [ZERO]
static constexpr size_t OFF_F    = 0x990000;  // f32 [16384*16] features
static constexpr size_t OFF_M    = 0xA90000;  // f32 [1024*1024] M = T2(Chat)
// end 0xE90000 (~15.6 MB of ws used)

typedef float f32x4 __attribute__((ext_vector_type(4)));
typedef short bf16x8 __attribute__((ext_vector_type(8)));
typedef unsigned int u32x4v __attribute__((ext_vector_type(4)));

// ---------- wave helpers ----------
__device__ __forceinline__ float wsumf(float v){
  #pragma unroll
  for (int off=32; off; off>>=1) v += __shfl_xor(v, off, 64);
  return v;
}
__device__ __forceinline__ float wminf(float v){
  #pragma unroll
  for (int off=32; off; off>>=1) v = fminf(v, __shfl_xor(v, off, 64));
  return v;
}
__device__ __forceinline__ float wmaxf(float v){
  #pragma unroll
  for (int off=32; off; off>>=1) v = fmaxf(v, __shfl_xor(v, off, 64));
  return v;
}
// broadcast lane l's value (l wave-uniform) -> v_readlane_b32
__device__ __forceinline__ float lanebc(float x, int l){
  return __int_as_float(__builtin_amdgcn_readlane(__float_as_int(x), l));
}
// 64-lane sum: DPP row_shr tree accumulates toward HIGH lanes -> row sums
// land in lanes 15/31/47/63; readlane those 4 and add. Result uniform.
__device__ __forceinline__ float wred64(float x){
  x += __int_as_float(__builtin_amdgcn_update_dpp(0, __float_as_int(x), 0x118, 0xf, 0xf, true)); // row_shr:8
  x += __int_as_float(__builtin_amdgcn_update_dpp(0, __float_as_int(x), 0x114, 0xf, 0xf, true)); // row_shr:4
  x += __int_as_float(__builtin_amdgcn_update_dpp(0, __float_as_int(x), 0x112, 0xf, 0xf, true)); // row_shr:2
  x += __int_as_float(__builtin_amdgcn_update_dpp(0, __float_as_int(x), 0x111, 0xf, 0xf, true)); // row_shr:1
  float s0 = lanebc(x, 15), s1 = lanebc(x, 31), s2 = lanebc(x, 47), s3 = lanebc(x, 63);
  return (s0 + s1) + (s2 + s3);
}

// ---------------- kernels ----------------

__global__ __launch_bounds__(256) void colsum_k(const float* __restrict__ X, float* __restrict__ cs){
  int b = blockIdx.x, t = threadIdx.x;
  float a0=0.f,a1=0.f,a2=0.f,a3=0.f;
  for (int r=0; r<64; ++r){
    const float4 v = *(const float4*)(X + (size_t)(b*64 + r)*1024 + t*4);
    a0 += v.x; a1 += v.y; a2 += v.z; a3 += v.w;
  }
  atomicAdd(&cs[t*4+0], a0); atomicAdd(&cs[t*4+1], a1);
  atomicAdd(&cs[t*4+2], a2); atomicAdd(&cs[t*4+3], a3);
}

// ---------------- MFMA SYRK: G += X^T X via 2-term bf16 split ----------------
// x = h + m + l, drop l (|l| <= 2^-16 |x|): products hh+hm+mh+mm -> ~2^-15
// relative on C. Output is compared in bf16 (2^-8 ulp) -> ~100x margin.
#define SYRK_SLICES 27
#define SYRK_KCHUNK 608   // 19 * 32

__device__ __forceinline__ f32x4 mfma32(bf16x8 a, bf16x8 b, f32x4 c){
  return __builtin_amdgcn_mfma_f32_16x16x32_bf16(a, b, c, 0, 0, 0);
}

__device__ __forceinline__ int lds_woff(int c, int chunk){
  return c*20 + (((chunk ^ ((c>>3)&3)) & 3) << 2);
}

// T2MODE=0: atomicAdd accumulate (multi-slice). T2MODE=1: single-slice
// direct write of 2*acc - I, mirrored (fuses formM; no memset needed).
template<int KCHUNK, int T2MODE>
__device__ __forceinline__ void syrk_mfma_body(const float* __restrict__ X, float* __restrict__ G, int KMAX){
  int bx = blockIdx.x;
  int tp = bx % 36, ks = bx / 36;
  int ti = 0, rem = tp;
  while (rem >= 8 - ti){ rem -= 8 - ti; ++ti; }
  int tj = ti + rem;                      // ti <= tj
  int k0 = ks * KCHUNK;
  int kend = k0 + KCHUNK; if (kend > KMAX) kend = KMAX;

  __shared__ __attribute__((aligned(16))) unsigned int LdsT[2][2][128][20];

  int t = threadIdx.x;
  int wid = t >> 6, lane = t & 63;
  int wr = wid >> 1, wc = wid & 1;
  int lm = lane & 15;
  int lk = lane >> 4;

  f32x4 acc[4][4];
  #pragma unroll
  for (int i=0;i<4;++i)
    #pragma unroll
    for (int j=0;j<4;++j) acc[i][j] = (f32x4){0.f,0.f,0.f,0.f};

  for (int kc = k0; kc < kend; kc += 32){
    __syncthreads();
    #pragma unroll
    for (int w=0; w<4; ++w){
      int job = t + 256*w;
      int c   = job & 127;
      int pk  = job >> 7;
      int p   = pk >> 2;
      int kpg = pk & 3;
      const float* src = X + (size_t)(kc + kpg*8)*1024 + (p ? tj : ti)*128 + c;
      float e[8];
      #pragma unroll
      for (int i=0;i<8;++i) e[i] = src[(size_t)i*1024];
      unsigned hh[8], mm[8];
      #pragma unroll
      for (int i=0;i<8;++i){
        unsigned u = __float_as_uint(e[i]);
        hh[i] = u & 0xFFFF0000u;
        float r1 = e[i] - __uint_as_float(hh[i]);
        mm[i] = __float_as_uint(r1) & 0xFFFF0000u;
      }
      u32x4v hp, mp;
      #pragma unroll
      for (int j=0;j<4;++j){
        hp[j] = (hh[2*j] >> 16) | hh[2*j+1];
        mp[j] = (mm[2*j] >> 16) | mm[2*j+1];
      }
      int wo = lds_woff(c, kpg);
      *(u32x4v*)(&LdsT[p][0][0][0] + wo) = hp;
      *(u32x4v*)(&LdsT[p][1][0][0] + wo) = mp;
    }
    __syncthreads();
    bf16x8 af[2][4], bg[2][4];
    #pragma unroll
    for (int fm=0; fm<4; ++fm){
      int ca = wr*64 + fm*16 + lm;
      int cb = wc*64 + fm*16 + lm;
      int woa = lds_woff(ca, lk);
      int wob = lds_woff(cb, lk);
      #pragma unroll
      for (int tm=0; tm<2; ++tm){
        af[tm][fm] = *(const bf16x8*)(&LdsT[0][tm][0][0] + woa);
        bg[tm][fm] = *(const bf16x8*)(&LdsT[1][tm][0][0] + wob);
      }
    }
    #pragma unroll
    for (int fm=0; fm<4; ++fm)
      #pragma unroll
      for (int fn=0; fn<4; ++fn){
        f32x4 a = acc[fm][fn];
        a = mfma32(af[0][fm], bg[0][fn], a);
        a = mfma32(af[0][fm], bg[1][fn], a);
        a = mfma32(af[1][fm], bg[0][fn], a);
        a = mfma32(af[1][fm], bg[1][fn], a);
        acc[fm][fn] = a;
      }
  }
  #pragma unroll
  for (int fm=0; fm<4; ++fm){
    int gi = ti*128 + wr*64 + fm*16 + lk*4;
    #pragma unroll
    for (int fn=0; fn<4; ++fn){
      int gj = tj*128 + wc*64 + fn*16 + lm;
      #pragma unroll
      for (int rg=0; rg<4; ++rg){
        if (T2MODE){
          int gii = gi + rg;
          float v = 2.f*acc[fm][fn][rg] - ((gii==gj) ? 1.f : 0.f);
          G[(size_t)gii*1024 + gj] = v;
          G[(size_t)gj*1024 + gii] = v;   // diagonal tiles: double-write identical
        } else {
          atomicAdd(&G[(size_t)(gi+rg)*1024 + gj], acc[fm][fn][rg]);
        }
      }
    }
  }
}

__global__ __launch_bounds__(256, 2) void syrk_mfma_k(const float* __restrict__ X, float* __restrict__ G){
  syrk_mfma_body<SYRK_KCHUNK, 0>(X, G, 16384);
}
// full-K single-slice: out = 2*X*X^T - I, mirrored. Grid = 36 blocks.
__global__ __launch_bounds__(256, 2) void syrkT2_k(const float* __restrict__ X, float* __restrict__ G){
  syrk_mfma_body<1024, 1>(X, G, 1024);
}

// trace of centered C from raw Gram diagonal + colsum; then scale factors.
__global__ __launch_bounds__(256) void trace_k(const float* __restrict__ G, const float* __restrict__ cs,
                                               float* __restrict__ scal){
  __shared__ float red[4];
  int t = threadIdx.x;
  float s = 0.f;
  #pragma unroll
  for (int w=0; w<4; ++w){
    int i = t + 256*w;
    float d = cs[i];
    s += G[(size_t)i*1025] - d*d*(1.0f/16384.0f);
  }
  s = wsumf(s);
  if ((t & 63) == 0) red[t >> 6] = s;
  __syncthreads();
  if (t == 0){
    float trD = (red[0]+red[1]+red[2]+red[3]) * (1.0f/1024.0f);
    float c = 1.40f * trD, a = 0.25f * trD;
    scal[0] = 0.5f*(c + a);       // mid
    scal[1] = 2.0f/(c - a);       // 1/e
  }
}

// fused centering + Chat scaling, mirrored write.
__global__ __launch_bounds__(256) void formCChat_k(float* __restrict__ C, const float* __restrict__ cs,
                                                   const float* __restrict__ scal){
  int g = blockIdx.x*256 + threadIdx.x;
  int i = g >> 10, j = g & 1023;
  if (j < i) return;
  float mid = scal[0], ie = scal[1];
  float v = C[g] - cs[i]*cs[j]*(1.0f/16384.0f);
  float h = ie*(v - ((i==j) ? mid : 0.f));
  C[g] = h;
  C[j*1024 + i] = h;
}

__global__ void rng_k(float* __restrict__ Y){
  int idx = blockIdx.x*256 + threadIdx.x;   // 65536
  unsigned h = (unsigned)idx * 2654435761u;
  h ^= h >> 16; h *= 2246822519u; h ^= h >> 13; h *= 3266489917u; h ^= h >> 16;
  Y[idx] = (float)(h & 0xFFFFFFu) * (2.0f/16777216.0f) - 1.0f;
}

__global__ __launch_bounds__(256) void mv_k(const float* __restrict__ Yt, const float* __restrict__ Cm, float* __restrict__ P){
  int bx = blockIdx.x;
  int nt = bx & 15, ks = bx >> 4;
  int n0 = nt*64, k0 = ks*64;
  __shared__ __attribute__((aligned(16))) float At[64][68];
  __shared__ __attribute__((aligned(16))) float Bt[64][68];
  int t = threadIdx.x;
  #pragma unroll
  for (int w=0; w<4; ++w){
    int job = t + 256*w;
    int m  = job >> 4, f4 = job & 15;
    float4 v = *(const float4*)(Yt + (size_t)m*1024 + k0 + f4*4);
    At[f4*4+0][m] = v.x; At[f4*4+1][m] = v.y; At[f4*4+2][m] = v.z; At[f4*4+3][m] = v.w;
    int kk = job >> 4, fn = job & 15;
    *(float4*)&Bt[kk][fn*4] = *(const float4*)(Cm + (size_t)(k0+kk)*1024 + n0 + fn*4);
  }
  __syncthreads();
  int tm = t & 15, tn = t >> 4;
  float acc[4][4];
  #pragma unroll
  for (int i=0;i<4;++i)
    #pragma unroll
    for (int j=0;j<4;++j) acc[i][j]=0.f;
  for (int kk=0; kk<64; ++kk){
    float4 a = *(const float4*)&At[kk][tm*4];
    float4 b = *(const float4*)&Bt[kk][tn*4];
    float av[4] = {a.x,a.y,a.z,a.w};
    float bv[4] = {b.x,b.y,b.z,b.w};
    #pragma unroll
    for (int i=0;i<4;++i)
      #pragma unroll
      for (int j=0;j<4;++j) acc[i][j] += av[i]*bv[j];
  }
  #pragma unroll
  for (int i=0;i<4;++i){
    float4 o; o.x=acc[i][0]; o.y=acc[i][1]; o.z=acc[i][2]; o.w=acc[i][3];
    *(float4*)(P + (size_t)(ks*64 + tm*4 + i)*1024 + n0 + tn*4) = o;
  }
}

__global__ __launch_bounds__(256) void combine_k(const float* __restrict__ P, const float* __restrict__ Tk1,
                                                 float* __restrict__ out, int mode){
  int idx = (blockIdx.x*256 + threadIdx.x)*4;
  float s0=0.f,s1=0.f,s2=0.f,s3=0.f;
  #pragma unroll
  for (int ks=0; ks<16; ++ks){
    const float4 p = *(const float4*)(P + (size_t)ks*65536 + idx);
    s0 += p.x; s1 += p.y; s2 += p.z; s3 += p.w;
  }
  float4 o;
  if (mode == 0){
    o.x=s0; o.y=s1; o.z=s2; o.w=s3;
  } else {
    const float4 t1 = *(const float4*)(Tk1 + idx);
    o.x = 2.f*s0 - t1.x; o.y = 2.f*s1 - t1.y;
    o.z = 2.f*s2 - t1.z; o.w = 2.f*s3 - t1.w;
  }
  *(float4*)(out+idx) = o;
}

__global__ __launch_bounds__(256) void gram_k(const float* __restrict__ A, const float* __restrict__ Bm, double* __restrict__ S){
  int bx = blockIdx.x;
  int i = bx >> 2, jg = bx & 3;
  __shared__ __attribute__((aligned(16))) float Ai[1024];
  __shared__ double red[16][17];
  int t = threadIdx.x;
  ((float4*)Ai)[t] = ((const float4*)(A + (size_t)i*1024))[t];
  __syncthreads();
  int jl = t >> 4, kp = t & 15;
  const float* Br = Bm + (size_t)(jg*16 + jl)*1024 + kp*64;
  const float* Ar = Ai + kp*64;
  double acc = 0.0;
  #pragma unroll 8
  for (int kk=0; kk<64; ++kk) acc += (double)Br[kk] * (double)Ar[kk];
  red[jl][kp] = acc;
  __syncthreads();
  if (t < 16){
    double s = 0.0;
    #pragma unroll
    for (int p2=0; p2<16; ++p2) s += red[t][p2];
    S[i*64 + jg*16 + t] = s;
  }
}

// fused fp64 Cholesky (wave 0, wave-synchronous) + triangular solve (1024 thr).
__global__ __launch_bounds__(1024) void cholsolve_k(const double* __restrict__ S,
                                                    const float* __restrict__ Yin, float* __restrict__ Qout){
  __shared__ double L[64][65];
  __shared__ double colD[64];
  __shared__ float LfS[64][65];   // lower factor; diag stores reciprocal
  int t = threadIdx.x;
  for (int e=t; e<4096; e+=1024) L[e>>6][e&63] = S[e];
  __syncthreads();
  if (t < 64){
    // single wave: lockstep; LDS broadcasts need no barrier (proven idiom)
    for (int k=0; k<64; ++k){
      double lkk = sqrt(fmax(L[k][k], 1e-280));
      double r = 1.0/lkk;
      double ck = (t > k) ? L[t][k]*r : 0.0;
      colD[t] = ck;
      if (t == k) L[k][k] = lkk;
      if (t > k)  L[t][k] = ck;
      #pragma unroll
      for (int j=0; j<64; j+=8){
        L[t][j+0] -= ck*colD[j+0];
        L[t][j+1] -= ck*colD[j+1];
        L[t][j+2] -= ck*colD[j+2];
        L[t][j+3] -= ck*colD[j+3];
        L[t][j+4] -= ck*colD[j+4];
        L[t][j+5] -= ck*colD[j+5];
        L[t][j+6] -= ck*colD[j+6];
        L[t][j+7] -= ck*colD[j+7];
      }
    }
    for (int e=t; e<4096; e+=64){
      int i = e >> 6, j = e & 63;
      LfS[i][j] = (j < i) ? (float)L[i][j] : ((j == i) ? (float)(1.0/L[i][i]) : 0.f);
    }
  }
  __syncthreads();
  // forward solve: thread t = column k of Y (1024 columns)
  float z[64];
  #pragma unroll
  for (int c=0; c<64; ++c){
    float v = Yin[(size_t)c*1024 + t];
    #pragma unroll
    for (int j=0; j<c; ++j) v -= LfS[c][j]*z[j];
    z[c] = v * LfS[c][c];
  }
  #pragma unroll
  for (int c=0; c<64; ++c) Qout[(size_t)c*1024 + t] = z[c];
}

// ---------- 256-thread fp32 64x64 symmetric top-16 eigensolver ----------
// v4: CODE-SIZE-MINIMIZED (rolled loops, LDS-resident HH) to stay I-cache-hot.
// Single-block serial kernel was ~150us across 3 unrolled variants; theory:
// instruction-fetch bound (~200KB straight-line code, cold L1I). All hot loops
// now rolled; HH operates on LDS A (stride 65 -> 2-way bank alias = free),
// wave-synchronous vS/qS broadcasts (idiom proven in R5 on this HW).
__global__ __launch_bounds__(256) void eig16_k(const double* __restrict__ Tin, float* __restrict__ V16){
  __shared__ float A[64][65];          // matrix; reflectors stored in lower columns
  __shared__ float vS[64], qS[64];
  __shared__ float dF[64], eF[64], e2F[64], kapS[64];
  __shared__ float lamF[16];
  __shared__ float IV[5][64][16];      // [0]=L factor f, [1]=recip pivot, [2]=DU, [3]=DU2, [4]=B
  __shared__ float W[16][68];
  int t = threadIdx.x;
  int r = t & 63, p4 = t >> 6;          // row, wave

  #pragma unroll 1
  for (int e=t; e<4096; e+=256){
    int i = e >> 6, j = e & 63;
    A[i][j] = (float)(0.5*(Tin[i*64+j] + Tin[(size_t)j*64+i]));
  }
  __syncthreads();

  // ---- Householder tridiagonalization: single wave, LDS-resident, rolled.
  if (p4 == 0){
    #pragma unroll 1
    for (int k=0; k<62; ++k){
      float ck = A[r][k];
      bool below = (r > k);
      float ckm = below ? ck : 0.f;
      float sig = wred64(ckm*ckm);
      float x1 = lanebc(ck, k+1);
      float rr = sqrtf(sig);
      float alpha = (x1 >= 0.f) ? -rr : rr;
      float kappa = sig - alpha*x1;
      float kinv = (kappa > 1e-30f) ? 1.f/kappa : 0.f;
      float v = ckm;
      if (r == k+1) v = x1 - alpha;
      if (kinv == 0.f) v = 0.f;
      if (r == 0){ eF[k] = (kinv==0.f) ? 0.f : alpha; kapS[k] = (kinv==0.f) ? 0.f : kappa; }
      if (r == k) dF[k] = ck;           // diagonal final before elimination k
      vS[r] = v;                        // wave-sync broadcast (in-order LDS)
      if (below) A[r][k] = v;           // reflector storage for back-transform
      int j0 = (k+1) & ~3;              // skip dead columns (vS=0 there)
      float p0=0.f,p1=0.f,p2=0.f,p3=0.f;
      #pragma unroll 1
      for (int j=j0; j<64; j+=4){
        p0 += A[r][j+0]*vS[j+0];
        p1 += A[r][j+1]*vS[j+1];
        p2 += A[r][j+2]*vS[j+2];
        p3 += A[r][j+3]*vS[j+3];
      }
      float pf = (p0+p1)+(p2+p3);
      float pi = below ? pf*kinv : 0.f;
      float vp = wred64(v*pi);
      float Kc = vp*0.5f*kinv;
      float q = below ? (pi - Kc*v) : 0.f;
      qS[r] = q;
      #pragma unroll 1
      for (int j=j0; j<64; j+=4){
        A[r][j+0] -= v*qS[j+0] + q*vS[j+0];   // no-op for j<=k (vS,qS zero)
        A[r][j+1] -= v*qS[j+1] + q*vS[j+1];
        A[r][j+2] -= v*qS[j+2] + q*vS[j+2];
        A[r][j+3] -= v*qS[j+3] + q*vS[j+3];
      }
    }
    if (r == 62) dF[62] = A[62][62];
    if (r == 63){ eF[62] = A[63][62]; dF[63] = A[63][63]; }
    if (r == 0){ eF[63] = 0.f; kapS[62] = 0.f; kapS[63] = 0.f; }
  }
  __syncthreads();
  if (t < 64) e2F[t] = eF[t]*eF[t];
  __syncthreads();

  // ---- Gershgorin bounds (redundant per wave) ----
  float em1 = (r > 0) ? fabsf(eF[r-1]) : 0.f;
  float ep  = fabsf(eF[r]);
  float glo = wminf(dF[r] - em1 - ep);
  float ghi = wmaxf(dF[r] + em1 + ep);
  float span = ghi - glo + 1.f;
  float lo = glo - 0.001f*span, hi = ghi + 0.001f*span;

  // ---- Sturm 16-point multisection: group (t>>4) owns eigen index 48+(t>>4)
  int eidx = t >> 4, g = t & 15;
  int m = 48 + eidx;
  #pragma unroll 1
  for (int it=0; it<7; ++it){
    float x = lo + (hi - lo)*((float)(g+1)*(1.0f/17.0f));
    float qq = dF[0] - x;
    int c = (qq < 0.f) ? 1 : 0;
    #pragma unroll 1
    for (int j=1; j<64; ++j){
      float aq = fabsf(qq);
      float qs = (aq < 1e-10f) ? ((qq < 0.f) ? -1e-10f : 1e-10f) : qq;
      qq = dF[j] - x - e2F[j-1]*__builtin_amdgcn_rcpf(qs);
      c += (qq < 0.f) ? 1 : 0;
    }
    float cl = (c <= m) ? x : -3.4e38f;
    float ch = (c >  m) ? x :  3.4e38f;
    #pragma unroll
    for (int off=1; off<16; off<<=1){
      cl = fmaxf(cl, __shfl_xor(cl, off, 64));
      ch = fminf(ch, __shfl_xor(ch, off, 64));
    }
    lo = fmaxf(lo, cl);
    hi = fminf(hi, ch);
  }
  if (g == 0) lamF[eidx] = 0.5f*(lo + hi);
  __syncthreads();

  // ---- inverse iteration (lanes 0..15): LU + 2 solves, rolled loops
  if (t < 16){
    float lam = lamF[t];
    const float PIVF = 1e-6f;
    #pragma unroll 1
    for (int i=0; i<64; ++i){
      unsigned hsh = (unsigned)(i*131 + t*1009 + 7);
      hsh ^= hsh >> 13; hsh *= 2654435761u; hsh ^= hsh >> 16;
      IV[4][i][t] = (float)(hsh & 0xFFFF) * (1.5f/65536.0f) + 0.25f;
    }
    unsigned long long piv = 0ull;
    float dcur = dF[0] - lam;
    float ducur = eF[0];
    #pragma unroll 1
    for (int i=0; i<63; ++i){
      float dli = eF[i];
      float dnext = dF[i+1] - lam;
      float eip1 = (i < 62) ? eF[i+1] : 0.f;
      bool sw = fabsf(dcur) < fabsf(dli);
      float dd = dcur;
      if (fabsf(dd) < PIVF) dd = (dd < 0.f) ? -PIVF : PIVF;
      float f = sw ? (dcur*__builtin_amdgcn_rcpf(dli)) : (dli*__builtin_amdgcn_rcpf(dd));
      float ddst = sw ? dli : dd;
      float dust = sw ? dnext : ducur;
      float du2  = sw ? eip1 : 0.f;
      float dnew = sw ? (ducur - f*dnext) : (dnext - f*ducur);
      float dunew= sw ? (-f*eip1) : eip1;
      if (sw) piv |= (1ull << i);
      IV[0][i][t] = f;
      float dc = ddst; if (fabsf(dc) < PIVF) dc = (dc < 0.f) ? -PIVF : PIVF;
      IV[1][i][t] = __builtin_amdgcn_rcpf(dc);
      IV[2][i][t] = dust;
      IV[3][i][t] = du2;
      dcur = dnew; ducur = dunew;
    }
    { float dc = dcur; if (fabsf(dc) < PIVF) dc = (dc < 0.f) ? -PIVF : PIVF; IV[1][63][t] = __builtin_amdgcn_rcpf(dc); }
    float ss = 0.f;
    #pragma unroll 1
    for (int iter=0; iter<2; ++iter){
      float scale = (iter == 0) ? 1.f : rsqrtf(fmaxf(ss, 1e-30f));
      float b = IV[4][0][t]*scale;
      #pragma unroll 1
      for (int i=0; i<63; ++i){
        float bn = IV[4][i+1][t]*scale;
        float f = IV[0][i][t];
        bool sw = (piv >> i) & 1ull;
        float keep = sw ? bn : b;
        float bnew = (sw ? b : bn) - f*keep;
        IV[4][i][t] = keep;
        b = bnew;
      }
      ss = 0.f;
      float x1v = b * IV[1][63][t];
      IV[4][63][t] = x1v; ss += x1v*x1v;
      float x0v = (IV[4][62][t] - IV[2][62][t]*x1v) * IV[1][62][t];
      IV[4][62][t] = x0v; ss += x0v*x0v;
      float xp1 = x0v, xp2 = x1v;
      #pragma unroll 1
      for (int i=61; i>=0; --i){
        float xi = (IV[4][i][t] - IV[2][i][t]*xp1 - IV[3][i][t]*xp2) * IV[1][i][t];
        IV[4][i][t] = xi; ss += xi*xi;
        xp2 = xp1; xp1 = xi;
      }
    }
    #pragma unroll 1
    for (int i=0; i<64; ++i) W[t][i] = IV[4][i][t];   // MGS normalizes
  }
  __syncthreads();

  // ---- MGS re-orth: wave 0 computes/writes, all threads hit barriers ----
  #pragma unroll 1
  for (int c=0; c<16; ++c){
    float wi = (t < 64) ? W[c][t] : 0.f;
    float s2 = wred64(wi*wi);
    float rn = rsqrtf(fmaxf(s2, 1e-30f));
    wi *= rn;
    if (t < 64) W[c][t] = wi;
    __syncthreads();
    #pragma unroll 1
    for (int c2=c+1; c2<16; ++c2){
      float w2 = (t < 64) ? W[c2][t] : 0.f;
      float d2 = wred64(wi*w2);
      if (t < 64) W[c2][t] -= d2*wi;
    }
    __syncthreads();
  }

  // ---- back-transform: 4 vecs/wave, 16 lanes/vec, no barriers needed ----
  int cL = (p4 << 2) + (r >> 4);        // eigvec index 0..15
  int part = r & 15;                    // 16 parts x 4 elements
  #pragma unroll 1
  for (int k=61; k>=0; --k){
    float kpd = kapS[k];
    if (kpd == 0.f) continue;           // wave-uniform
    float invk = 1.f/kpd;
    float vv[4];
    float ps = 0.f;
    #pragma unroll
    for (int mm=0; mm<4; ++mm){
      int i = part*4 + mm;
      vv[mm] = (i > k) ? A[i][k] : 0.f;
      ps += vv[mm]*W[cL][i];
    }
    ps += __shfl_xor(ps, 1, 64);
    ps += __shfl_xor(ps, 2, 64);
    ps += __shfl_xor(ps, 4, 64);
    ps += __shfl_xor(ps, 8, 64);
    float sc = ps * invk;
    #pragma unroll
    for (int mm=0; mm<4; ++mm){
      int i = part*4 + mm;
      W[cL][i] -= vv[mm]*sc;
    }
  }
  __syncthreads();

  #pragma unroll 1
  for (int e=t; e<1024; e+=256){
    int j = e >> 4, c = e & 15;
    V16[e] = W[c][j];
  }
}

__global__ __launch_bounds__(256) void buildUt_k(const float* __restrict__ V16,
                                                 const float* __restrict__ Qt, float* __restrict__ Ut, float* __restrict__ UtT){
  int bx = blockIdx.x;
  int c = bx & 15, kc = bx >> 4;
  int k = kc*256 + threadIdx.x;
  float acc = 0.f;
  #pragma unroll
  for (int j=0; j<64; ++j) acc += V16[j*16 + c] * Qt[(size_t)j*1024 + k];
  Ut[(size_t)c*1024 + k] = acc;
  UtT[(size_t)k*16 + c] = acc;
}

__global__ void s16_k(const float* __restrict__ cs, const float* __restrict__ Ut, float* __restrict__ s16){
  __shared__ float red[16][17];
  int t = threadIdx.x;
  int c = t & 15, part = t >> 4;
  float acc = 0.f;
  for (int d=0; d<64; ++d) acc += cs[part*64 + d] * Ut[(size_t)c*1024 + part*64 + d];
  red[c][part] = acc;
  __syncthreads();
  if (t < 16){
    float s = 0.f;
    #pragma unroll
    for (int p2=0; p2<16; ++p2) s += red[t][p2];
    s16[t] = s * (1.0f/16384.0f);
  }
}

__global__ __launch_bounds__(256) void proj_k(const float* __restrict__ X, const float* __restrict__ UtT,
                                              const float* __restrict__ s16, float* __restrict__ F){
  int r0 = blockIdx.x * 64;
  int t = threadIdx.x;
  __shared__ __attribute__((aligned(16))) float uts[16384];   // [1024][16]
  #pragma unroll
  for (int w=0; w<16; ++w)
    ((float4*)uts)[t + 256*w] = ((const float4*)UtT)[t + 256*w];
  __syncthreads();
  int row = t & 63, kp = t >> 6;
  const float* xr = X + (size_t)(r0 + row)*1024 + kp*256;
  const float* ut = uts + kp*256*16;
  float acc[16];
  #pragma unroll
  for (int c=0;c<16;++c) acc[c] = 0.f;
  for (int dd=0; dd<256; dd+=4){
    float4 xv4 = *(const float4*)(xr + dd);
    float xv[4] = {xv4.x, xv4.y, xv4.z, xv4.w};
    #pragma unroll
    for (int u=0; u<4; ++u)
      #pragma unroll
      for (int c=0;c<16;++c) acc[c] += xv[u] * ut[(dd+u)*16 + c];
  }
  __shared__ float part[4][64][16];
  #pragma unroll
  for (int c=0;c<16;++c) part[kp][row][c] = acc[c];
  __syncthreads();
  int cq = t >> 6;
  #pragma unroll
  for (int ccx=0; ccx<4; ++ccx){
    int c = cq*4 + ccx;
    float v = part[0][row][c] + part[1][row][c] + part[2][row][c] + part[3][row][c] - s16[c];
    F[(size_t)(r0 + row)*16 + c] = v;
  }
}

__global__ __launch_bounds__(256) void stats_k(const float* __restrict__ F, const int* __restrict__ lbl, float* __restrict__ SG){
  __shared__ float st[10][154];
  int t = threadIdx.x;
  for (int e=t; e<1540; e+=256) st[e/154][e%154] = 0.f;
  __syncthreads();
  int r = blockIdx.x*256 + t;
  float f[16];
  #pragma unroll
  for (int w=0; w<4; ++w){
    float4 v = *(const float4*)(F + (size_t)r*16 + w*4);
    f[w*4+0]=v.x; f[w*4+1]=v.y; f[w*4+2]=v.z; f[w*4+3]=v.w;
  }
  int c = lbl[r];
  if ((unsigned)c < 10u){
    float* bs = &st[c][0];
    atomicAdd(&bs[0], 1.f);
    #pragma unroll
    for (int a=0;a<16;++a) atomicAdd(&bs[1+a], f[a]);
    int sidx = 17;
    #pragma unroll
    for (int a=0;a<16;++a)
      #pragma unroll
      for (int b2=a;b2<16;++b2) atomicAdd(&bs[sidx++], f[a]*f[b2]);
  }
  __syncthreads();
  for (int e=t; e<1530; e+=256) atomicAdd(&SG[e], st[e/153][e%153]);
}

__global__ __launch_bounds__(256) void final_k(const float* __restrict__ SG, float* __restrict__ out){
  __shared__ double cnt[10], safe[10], ldet[10];
  __shared__ double mean[10][16];
  __shared__ double Sig[10][16][16];
  __shared__ double Inv[10][16][16];
  __shared__ double red[128];
  int t = threadIdx.x;
  if (t < 10){
    double c0 = (double)SG[t*153];
    cnt[t] = c0; safe[t] = (c0 > 0.0) ? c0 : 1.0;
  }
  __syncthreads();
  for (int e=t; e<160; e+=256){
    int c = e >> 4, a = e & 15;
    mean[c][a] = (double)SG[c*153 + 1 + a] / safe[c];
  }
  __syncthreads();
  for (int e=t; e<2560; e+=256){
    int c = e >> 8, ab = e & 255, a = ab >> 4, b2 = ab & 15;
    int lo = a < b2 ? a : b2, hi = a < b2 ? b2 : a;
    int ti = lo*(33 - lo)/2 + (hi - lo);
    Sig[c][a][b2] = (double)SG[c*153 + 17 + ti]/safe[c] - mean[c][a]*mean[c][b2] + ((a==b2)?1.0:0.0);
  }
  __syncthreads();
  if (t < 10){
    for (int a=0;a<16;++a)
      for (int b2=0;b2<16;++b2) Inv[t][a][b2] = Sig[t][a][b2];
    double ld2 = 0.0;
    for (int k=0;k<16;++k){
      double v = Inv[t][k][k];
      for (int j=0;j<k;++j) v -= Inv[t][k][j]*Inv[t][k][j];
      v = fmax(v, 1e-280);
      double lkk = sqrt(v);
      Inv[t][k][k] = lkk; ld2 += log(lkk);
      for (int i=k+1;i<16;++i){
        double w = Inv[t][i][k];
        for (int j=0;j<k;++j) w -= Inv[t][i][j]*Inv[t][k][j];
        Inv[t][i][k] = w / lkk;
      }
    }
    ldet[t] = 2.0*ld2;
    for (int j=0;j<16;++j){
      double dj = 1.0 / Inv[t][j][j];
      Inv[t][j][j] = dj;
      for (int i=j+1;i<16;++i){
        double ssum = Inv[t][i][j]*dj;
        for (int k=j+1;k<i;++k) ssum += Inv[t][i][k]*Inv[t][k][j];
        Inv[t][i][j] = -ssum / Inv[t][i][i];
      }
    }
    double dg[16];
    #pragma unroll
    for (int a=0;a<16;++a){
      double s2 = 0.0;
      for (int k=a;k<16;++k){ double x = Inv[t][k][a]; s2 += x*x; }
      dg[a] = s2;
    }
    for (int a=0;a<16;++a)
      for (int b2=a+1;b2<16;++b2){
        double s2 = 0.0;
        for (int k=b2;k<16;++k) s2 += Inv[t][k][a]*Inv[t][k][b2];
        Inv[t][a][b2] = s2;
      }
    for (int a=0;a<16;++a) Inv[t][a][a] = dg[a];
    for (int a=0;a<16;++a)
      for (int b2=a+1;b2<16;++b2) Inv[t][b2][a] = Inv[t][a][b2];
  }
  __syncthreads();
  double contrib = 0.0;
  if (t < 100){
    int i = t/10, j = t%10;
    if (i != j && cnt[i] > 0.0 && cnt[j] > 0.0){
      double tr = 0.0;
      for (int a=0;a<16;++a)
        for (int b2=0;b2<16;++b2) tr += Inv[j][a][b2]*Sig[i][b2][a];
      double dm[16];
      #pragma unroll
      for (int a=0;a<16;++a) dm[a] = mean[j][a] - mean[i][a];
      double mah = 0.0;
      for (int a=0;a<16;++a){
        double rs = 0.0;
        for (int b2=0;b2<16;++b2) rs += Inv[j][a][b2]*dm[b2];
        mah += dm[a]*rs;
      }
      double kl = 0.5*(tr + mah - 16.0 + ldet[j] - ldet[i]);
      contrib = kl * cnt[i]*cnt[j];
    }
  }
  if (t < 128) red[t] = contrib;
  __syncthreads();
  for (int off=64; off>0; off >>= 1){
    if (t < off) red[t] += red[t+off];
    __syncthreads();
  }
  if (t == 0) out[0] = (float)(red[0] / (16384.0*16384.0*16384.0));
}

// ---------------- host ----------------
extern "C" void kernel_launch(void* const* d_in, const int* in_sizes, int n_in,
                              void* d_out, int out_size, void* d_ws, size_t ws_size,
                              hipStream_t stream){
  (void)in_sizes; (void)n_in; (void)out_size; (void)ws_size;
  const float* X  = (const float*)d_in[0];
  const int* lbl  = (const int*)d_in[1];
  char* ws = (char*)d_ws;
  float*  C    = (float*)(ws + OFF_C);     // Gram -> Chat -> M4
  float*  Mm   = (float*)(ws + OFF_M);     // M  = T2(Chat)
  float*  P    = (float*)(ws + OFF_P);     // M2 = T4(Chat), then mv partials
  float*  Y0   = (float*)(ws + OFF_Y0);
  float*  Y1   = (float*)(ws + OFF_Y1);
  float*  Y2   = (float*)(ws + OFF_Y2);
  float*  Y3   = (float*)(ws + OFF_Y3);
  float*  CQ   = (float*)(ws + OFF_CQ);
  double* S64  = (double*)(ws + OFF_S64);
  double* T64  = (double*)(ws + OFF_T64);
  float*  V16  = (float*)(ws + OFF_V16);
  float*  UT   = (float*)(ws + OFF_UT);
  float*  UTT  = (float*)(ws + OFF_UTT);
  float*  S16  = (float*)(ws + OFF_S16);
  float*  CS   = (float*)(ws + OFF_CS);
  float*  SCAL = (float*)(ws + OFF_SCAL);
  float*  STAT = (float*)(ws + OFF_STAT);
  float*  F    = (float*)(ws + OFF_F);
  float*  OUT  = (float*)d_out;

  hipMemsetAsync(C, 0, 4*1024*1024, stream);
  hipMemsetAsync(ws + OFF_CS, 0, 12800, stream);   // CS + TR + SCAL + STAT

  colsum_k<<<256, 256, 0, stream>>>(X, CS);
  syrk_mfma_k<<<36*SYRK_SLICES, 256, 0, stream>>>(X, C);
  trace_k<<<1, 256, 0, stream>>>(C, CS, SCAL);
  formCChat_k<<<4096, 256, 0, stream>>>(C, CS, SCAL);  // C := Chat
  syrkT2_k<<<36, 256, 0, stream>>>(C, Mm);             // Mm = T2(Chat) (fused formM)
  syrkT2_k<<<36, 256, 0, stream>>>(Mm, P);             // P  = T4(Chat)
  syrkT2_k<<<36, 256, 0, stream>>>(P, C);              // C  = T8(Chat)  (M4)
  rng_k<<<256, 256, 0, stream>>>(Y0);

  // stage filter: T16(Chat)U = T2(M4)U = 2*M4*(M4*U) - U  (2 mv+combine pairs)
  auto cheb2 = [&](float* U, float* Wb, float* Ob){
    mv_k<<<256, 256, 0, stream>>>(U, C, P);
    combine_k<<<64, 256, 0, stream>>>(P, U, Wb, 0);          // Wb = M4*U
    mv_k<<<256, 256, 0, stream>>>(Wb, C, P);
    combine_k<<<64, 256, 0, stream>>>(P, U, Ob, 1);          // Ob = 2*M4*Wb - U
  };
  auto cholqr = [&](float* Yin, float* Qout){
    gram_k<<<256, 256, 0, stream>>>(Yin, Yin, S64);
    cholsolve_k<<<1, 1024, 0, stream>>>(S64, Yin, Qout);
  };

  // stage 1: filter random block, single CholQR (conditioning only)
  cheb2(Y0, Y1, Y2);
  cholqr(Y2, Y0);                      // Q1 = Y0
  // stage 2 + CholQR2 (full orthonormality before RR)
  cheb2(Y0, Y1, Y2);
  cholqr(Y2, Y1);
  cholqr(Y1, Y3);                      // Qf = Y3

  // Rayleigh-Ritz in M-space: T = Q^T M Q
  mv_k<<<256, 256, 0, stream>>>(Y3, Mm, P);
  combine_k<<<64, 256, 0, stream>>>(P, Y3, CQ, 0);     // CQ = M Q
  gram_k<<<256, 256, 0, stream>>>(Y3, CQ, T64);
  eig16_k<<<1, 256, 0, stream>>>(T64, V16);
  buildUt_k<<<64, 256, 0, stream>>>(V16, Y3, UT, UTT);

  // project and GMM loss
  s16_k<<<1, 256, 0, stream>>>(CS, UT, S16);
  proj_k<<<256, 256, 0, stream>>>(X, UTT, S16, F);
  stats_k<<<64, 256, 0, stream>>>(F, lbl, STAT);
  final_k<<<1, 256, 0, stream>>>(STAT, OUT);
}

// Round 11
// 1085.891 us; speedup vs baseline: 1.0981x; 1.0981x over previous
//
#include <hip/hip_runtime.h>
#include <math.h>

// ---------------- problem constants (fixed inputs: key 0) ----------------
#define BN 16384
#define DN 1024

// ---------------- workspace layout (bytes, all 256-aligned) ----------------
static constexpr size_t OFF_C    = 0x000000;  // f32 [1024*1024]  G -> Chat -> M4  [ZERO]
static constexpr size_t OFF_P    = 0x400000;  // f32 [1024*1024]  M2 (T4) then mv partials
static constexpr size_t OFF_Y0   = 0x800000;  // f32 [64][1024]
static constexpr size_t OFF_Y1   = 0x840000;
static constexpr size_t OFF_Y2   = 0x880000;
static constexpr size_t OFF_Y3   = 0x8C0000;
static constexpr size_t OFF_CQ   = 0x900000;  // f32 [64][1024]
static constexpr size_t OFF_S64  = 0x940000;  // f64 [64*64] gram
static constexpr size_t OFF_T64  = 0x950000;  // f64 [64*64] RR matrix (in M-space)
static constexpr size_t OFF_V16  = 0x958000;  // f32 [64*16] top-16 eigvecs
static constexpr size_t OFF_UT   = 0x960000;  // f32 [16][1024]
static constexpr size_t OFF_UTT  = 0x970000;  // f32 [1024][16]
static constexpr size_t OFF_S16  = 0x980000;  // f32 [16]
static constexpr size_t OFF_CS   = 0x980100;  // f32 [1024] colsum           [ZERO]
static constexpr size_t OFF_TR   = 0x981100;  // f32 [1] trace               [ZERO]
static constexpr size_t OFF_SCAL = 0x981200;  // f32 [2] mid, inv_e
static constexpr size_t OFF_STAT = 0x981300;  // f32 [10*153] stats          [ZERO]
static constexpr size_t OFF_F    = 0x990000;  // f32 [16384*16] features
static constexpr size_t OFF_M    = 0xA90000;  // f32 [1024*1024] M = T2(Chat)
// end 0xE90000 (~15.6 MB of ws used)

typedef float f32x4 __attribute__((ext_vector_type(4)));
typedef short bf16x8 __attribute__((ext_vector_type(8)));
typedef unsigned int u32x4v __attribute__((ext_vector_type(4)));

// ---------- wave helpers ----------
__device__ __forceinline__ float wsumf(float v){
  #pragma unroll
  for (int off=32; off; off>>=1) v += __shfl_xor(v, off, 64);
  return v;
}
__device__ __forceinline__ float wminf(float v){
  #pragma unroll
  for (int off=32; off; off>>=1) v = fminf(v, __shfl_xor(v, off, 64));
  return v;
}
__device__ __forceinline__ float wmaxf(float v){
  #pragma unroll
  for (int off=32; off; off>>=1) v = fmaxf(v, __shfl_xor(v, off, 64));
  return v;
}
// broadcast lane l's value (l wave-uniform) -> v_readlane_b32
__device__ __forceinline__ float lanebc(float x, int l){
  return __int_as_float(__builtin_amdgcn_readlane(__float_as_int(x), l));
}
// 64-lane sum: DPP row_shr tree accumulates toward HIGH lanes -> row sums
// land in lanes 15/31/47/63; readlane those 4 and add. Result uniform.
__device__ __forceinline__ float wred64(float x){
  x += __int_as_float(__builtin_amdgcn_update_dpp(0, __float_as_int(x), 0x118, 0xf, 0xf, true)); // row_shr:8
  x += __int_as_float(__builtin_amdgcn_update_dpp(0, __float_as_int(x), 0x114, 0xf, 0xf, true)); // row_shr:4
  x += __int_as_float(__builtin_amdgcn_update_dpp(0, __float_as_int(x), 0x112, 0xf, 0xf, true)); // row_shr:2
  x += __int_as_float(__builtin_amdgcn_update_dpp(0, __float_as_int(x), 0x111, 0xf, 0xf, true)); // row_shr:1
  float s0 = lanebc(x, 15), s1 = lanebc(x, 31), s2 = lanebc(x, 47), s3 = lanebc(x, 63);
  return (s0 + s1) + (s2 + s3);
}

// ---------------- kernels ----------------

__global__ __launch_bounds__(256) void colsum_k(const float* __restrict__ X, float* __restrict__ cs){
  int b = blockIdx.x, t = threadIdx.x;
  float a0=0.f,a1=0.f,a2=0.f,a3=0.f;
  for (int r=0; r<64; ++r){
    const float4 v = *(const float4*)(X + (size_t)(b*64 + r)*1024 + t*4);
    a0 += v.x; a1 += v.y; a2 += v.z; a3 += v.w;
  }
  atomicAdd(&cs[t*4+0], a0); atomicAdd(&cs[t*4+1], a1);
  atomicAdd(&cs[t*4+2], a2); atomicAdd(&cs[t*4+3], a3);
}

// ---------------- MFMA SYRK: G += X^T X via 2-term bf16 split ----------------
// x = h + m + l, drop l: products hh+hm+mh+mm -> ~2^-15 relative on C.
// Output is compared in bf16 (2^-8 ulp) -> ~100x margin.
#define SYRK_SLICES 27
#define SYRK_KCHUNK 608   // 19 * 32

__device__ __forceinline__ f32x4 mfma32(bf16x8 a, bf16x8 b, f32x4 c){
  return __builtin_amdgcn_mfma_f32_16x16x32_bf16(a, b, c, 0, 0, 0);
}

__device__ __forceinline__ int lds_woff(int c, int chunk){
  return c*20 + (((chunk ^ ((c>>3)&3)) & 3) << 2);
}

// T2MODE=0: atomicAdd accumulate (multi-slice). T2MODE=1: single-slice
// direct write of 2*acc - I, mirrored (fuses formM; no memset needed).
template<int KCHUNK, int T2MODE>
__device__ __forceinline__ void syrk_mfma_body(const float* __restrict__ X, float* __restrict__ G, int KMAX){
  int bx = blockIdx.x;
  int tp = bx % 36, ks = bx / 36;
  int ti = 0, rem = tp;
  while (rem >= 8 - ti){ rem -= 8 - ti; ++ti; }
  int tj = ti + rem;                      // ti <= tj
  int k0 = ks * KCHUNK;
  int kend = k0 + KCHUNK; if (kend > KMAX) kend = KMAX;

  __shared__ __attribute__((aligned(16))) unsigned int LdsT[2][2][128][20];

  int t = threadIdx.x;
  int wid = t >> 6, lane = t & 63;
  int wr = wid >> 1, wc = wid & 1;
  int lm = lane & 15;
  int lk = lane >> 4;

  f32x4 acc[4][4];
  #pragma unroll
  for (int i=0;i<4;++i)
    #pragma unroll
    for (int j=0;j<4;++j) acc[i][j] = (f32x4){0.f,0.f,0.f,0.f};

  for (int kc = k0; kc < kend; kc += 32){
    __syncthreads();
    #pragma unroll
    for (int w=0; w<4; ++w){
      int job = t + 256*w;
      int c   = job & 127;
      int pk  = job >> 7;
      int p   = pk >> 2;
      int kpg = pk & 3;
      const float* src = X + (size_t)(kc + kpg*8)*1024 + (p ? tj : ti)*128 + c;
      float e[8];
      #pragma unroll
      for (int i=0;i<8;++i) e[i] = src[(size_t)i*1024];
      unsigned hh[8], mm[8];
      #pragma unroll
      for (int i=0;i<8;++i){
        unsigned u = __float_as_uint(e[i]);
        hh[i] = u & 0xFFFF0000u;
        float r1 = e[i] - __uint_as_float(hh[i]);
        mm[i] = __float_as_uint(r1) & 0xFFFF0000u;
      }
      u32x4v hp, mp;
      #pragma unroll
      for (int j=0;j<4;++j){
        hp[j] = (hh[2*j] >> 16) | hh[2*j+1];
        mp[j] = (mm[2*j] >> 16) | mm[2*j+1];
      }
      int wo = lds_woff(c, kpg);
      *(u32x4v*)(&LdsT[p][0][0][0] + wo) = hp;
      *(u32x4v*)(&LdsT[p][1][0][0] + wo) = mp;
    }
    __syncthreads();
    bf16x8 af[2][4], bg[2][4];
    #pragma unroll
    for (int fm=0; fm<4; ++fm){
      int ca = wr*64 + fm*16 + lm;
      int cb = wc*64 + fm*16 + lm;
      int woa = lds_woff(ca, lk);
      int wob = lds_woff(cb, lk);
      #pragma unroll
      for (int tm=0; tm<2; ++tm){
        af[tm][fm] = *(const bf16x8*)(&LdsT[0][tm][0][0] + woa);
        bg[tm][fm] = *(const bf16x8*)(&LdsT[1][tm][0][0] + wob);
      }
    }
    #pragma unroll
    for (int fm=0; fm<4; ++fm)
      #pragma unroll
      for (int fn=0; fn<4; ++fn){
        f32x4 a = acc[fm][fn];
        a = mfma32(af[0][fm], bg[0][fn], a);
        a = mfma32(af[0][fm], bg[1][fn], a);
        a = mfma32(af[1][fm], bg[0][fn], a);
        a = mfma32(af[1][fm], bg[1][fn], a);
        acc[fm][fn] = a;
      }
  }
  #pragma unroll
  for (int fm=0; fm<4; ++fm){
    int gi = ti*128 + wr*64 + fm*16 + lk*4;
    #pragma unroll
    for (int fn=0; fn<4; ++fn){
      int gj = tj*128 + wc*64 + fn*16 + lm;
      #pragma unroll
      for (int rg=0; rg<4; ++rg){
        if (T2MODE){
          int gii = gi + rg;
          float v = 2.f*acc[fm][fn][rg] - ((gii==gj) ? 1.f : 0.f);
          G[(size_t)gii*1024 + gj] = v;
          G[(size_t)gj*1024 + gii] = v;   // diagonal tiles: double-write identical
        } else {
          atomicAdd(&G[(size_t)(gi+rg)*1024 + gj], acc[fm][fn][rg]);
        }
      }
    }
  }
}

__global__ __launch_bounds__(256, 2) void syrk_mfma_k(const float* __restrict__ X, float* __restrict__ G){
  syrk_mfma_body<SYRK_KCHUNK, 0>(X, G, 16384);
}
// full-K single-slice: out = 2*X*X^T - I, mirrored. Grid = 36 blocks.
__global__ __launch_bounds__(256, 2) void syrkT2_k(const float* __restrict__ X, float* __restrict__ G){
  syrk_mfma_body<1024, 1>(X, G, 1024);
}

// trace of centered C from raw Gram diagonal + colsum; then scale factors.
__global__ __launch_bounds__(256) void trace_k(const float* __restrict__ G, const float* __restrict__ cs,
                                               float* __restrict__ scal){
  __shared__ float red[4];
  int t = threadIdx.x;
  float s = 0.f;
  #pragma unroll
  for (int w=0; w<4; ++w){
    int i = t + 256*w;
    float d = cs[i];
    s += G[(size_t)i*1025] - d*d*(1.0f/16384.0f);
  }
  s = wsumf(s);
  if ((t & 63) == 0) red[t >> 6] = s;
  __syncthreads();
  if (t == 0){
    float trD = (red[0]+red[1]+red[2]+red[3]) * (1.0f/1024.0f);
    float c = 1.40f * trD, a = 0.25f * trD;
    scal[0] = 0.5f*(c + a);       // mid
    scal[1] = 2.0f/(c - a);       // 1/e
  }
}

// fused centering + Chat scaling, mirrored write.
__global__ __launch_bounds__(256) void formCChat_k(float* __restrict__ C, const float* __restrict__ cs,
                                                   const float* __restrict__ scal){
  int g = blockIdx.x*256 + threadIdx.x;
  int i = g >> 10, j = g & 1023;
  if (j < i) return;
  float mid = scal[0], ie = scal[1];
  float v = C[g] - cs[i]*cs[j]*(1.0f/16384.0f);
  float h = ie*(v - ((i==j) ? mid : 0.f));
  C[g] = h;
  C[j*1024 + i] = h;
}

__global__ void rng_k(float* __restrict__ Y){
  int idx = blockIdx.x*256 + threadIdx.x;   // 65536
  unsigned h = (unsigned)idx * 2654435761u;
  h ^= h >> 16; h *= 2246822519u; h ^= h >> 13; h *= 3266489917u; h ^= h >> 16;
  Y[idx] = (float)(h & 0xFFFFFFu) * (2.0f/16777216.0f) - 1.0f;
}

__global__ __launch_bounds__(256) void mv_k(const float* __restrict__ Yt, const float* __restrict__ Cm, float* __restrict__ P){
  int bx = blockIdx.x;
  int nt = bx & 15, ks = bx >> 4;
  int n0 = nt*64, k0 = ks*64;
  __shared__ __attribute__((aligned(16))) float At[64][68];
  __shared__ __attribute__((aligned(16))) float Bt[64][68];
  int t = threadIdx.x;
  #pragma unroll
  for (int w=0; w<4; ++w){
    int job = t + 256*w;
    int m  = job >> 4, f4 = job & 15;
    float4 v = *(const float4*)(Yt + (size_t)m*1024 + k0 + f4*4);
    At[f4*4+0][m] = v.x; At[f4*4+1][m] = v.y; At[f4*4+2][m] = v.z; At[f4*4+3][m] = v.w;
    int kk = job >> 4, fn = job & 15;
    *(float4*)&Bt[kk][fn*4] = *(const float4*)(Cm + (size_t)(k0+kk)*1024 + n0 + fn*4);
  }
  __syncthreads();
  int tm = t & 15, tn = t >> 4;
  float acc[4][4];
  #pragma unroll
  for (int i=0;i<4;++i)
    #pragma unroll
    for (int j=0;j<4;++j) acc[i][j]=0.f;
  for (int kk=0; kk<64; ++kk){
    float4 a = *(const float4*)&At[kk][tm*4];
    float4 b = *(const float4*)&Bt[kk][tn*4];
    float av[4] = {a.x,a.y,a.z,a.w};
    float bv[4] = {b.x,b.y,b.z,b.w};
    #pragma unroll
    for (int i=0;i<4;++i)
      #pragma unroll
      for (int j=0;j<4;++j) acc[i][j] += av[i]*bv[j];
  }
  #pragma unroll
  for (int i=0;i<4;++i){
    float4 o; o.x=acc[i][0]; o.y=acc[i][1]; o.z=acc[i][2]; o.w=acc[i][3];
    *(float4*)(P + (size_t)(ks*64 + tm*4 + i)*1024 + n0 + tn*4) = o;
  }
}

__global__ __launch_bounds__(256) void combine_k(const float* __restrict__ P, const float* __restrict__ Tk1,
                                                 float* __restrict__ out, int mode){
  int idx = (blockIdx.x*256 + threadIdx.x)*4;
  float s0=0.f,s1=0.f,s2=0.f,s3=0.f;
  #pragma unroll
  for (int ks=0; ks<16; ++ks){
    const float4 p = *(const float4*)(P + (size_t)ks*65536 + idx);
    s0 += p.x; s1 += p.y; s2 += p.z; s3 += p.w;
  }
  float4 o;
  if (mode == 0){
    o.x=s0; o.y=s1; o.z=s2; o.w=s3;
  } else {
    const float4 t1 = *(const float4*)(Tk1 + idx);
    o.x = 2.f*s0 - t1.x; o.y = 2.f*s1 - t1.y;
    o.z = 2.f*s2 - t1.z; o.w = 2.f*s3 - t1.w;
  }
  *(float4*)(out+idx) = o;
}

__global__ __launch_bounds__(256) void gram_k(const float* __restrict__ A, const float* __restrict__ Bm, double* __restrict__ S){
  int bx = blockIdx.x;
  int i = bx >> 2, jg = bx & 3;
  __shared__ __attribute__((aligned(16))) float Ai[1024];
  __shared__ double red[16][17];
  int t = threadIdx.x;
  ((float4*)Ai)[t] = ((const float4*)(A + (size_t)i*1024))[t];
  __syncthreads();
  int jl = t >> 4, kp = t & 15;
  const float* Br = Bm + (size_t)(jg*16 + jl)*1024 + kp*64;
  const float* Ar = Ai + kp*64;
  double acc = 0.0;
  #pragma unroll 8
  for (int kk=0; kk<64; ++kk) acc += (double)Br[kk] * (double)Ar[kk];
  red[jl][kp] = acc;
  __syncthreads();
  if (t < 16){
    double s = 0.0;
    #pragma unroll
    for (int p2=0; p2<16; ++p2) s += red[t][p2];
    S[i*64 + jg*16 + t] = s;
  }
}

// fused fp64 Cholesky + triangular solve. Grid = 4 blocks x 256 threads:
// each block REDUNDANTLY factors the same 64x64 (wave 0, ~5us, bit-identical)
// then solves its 256-column quarter (1 col/thread) -> 4x solve parallelism.
__global__ __launch_bounds__(256) void cholsolve_k(const double* __restrict__ S,
                                                   const float* __restrict__ Yin, float* __restrict__ Qout){
  __shared__ double L[64][65];
  __shared__ double colD[64];
  __shared__ float LfS[64][65];   // lower factor; diag stores reciprocal
  int t = threadIdx.x;
  for (int e=t; e<4096; e+=256) L[e>>6][e&63] = S[e];
  __syncthreads();
  if (t < 64){
    // single wave: lockstep; LDS broadcasts need no barrier (proven idiom)
    for (int k=0; k<64; ++k){
      double lkk = sqrt(fmax(L[k][k], 1e-280));
      double r = 1.0/lkk;
      double ck = (t > k) ? L[t][k]*r : 0.0;
      colD[t] = ck;
      if (t == k) L[k][k] = lkk;
      if (t > k)  L[t][k] = ck;
      #pragma unroll
      for (int j=0; j<64; j+=8){
        L[t][j+0] -= ck*colD[j+0];
        L[t][j+1] -= ck*colD[j+1];
        L[t][j+2] -= ck*colD[j+2];
        L[t][j+3] -= ck*colD[j+3];
        L[t][j+4] -= ck*colD[j+4];
        L[t][j+5] -= ck*colD[j+5];
        L[t][j+6] -= ck*colD[j+6];
        L[t][j+7] -= ck*colD[j+7];
      }
    }
    for (int e=t; e<4096; e+=64){
      int i = e >> 6, j = e & 63;
      LfS[i][j] = (j < i) ? (float)L[i][j] : ((j == i) ? (float)(1.0/L[i][i]) : 0.f);
    }
  }
  __syncthreads();
  // forward solve: this block's column range
  int col = blockIdx.x*256 + t;
  float z[64];
  #pragma unroll
  for (int c=0; c<64; ++c){
    float v = Yin[(size_t)c*1024 + col];
    #pragma unroll
    for (int j=0; j<c; ++j) v -= LfS[c][j]*z[j];
    z[c] = v * LfS[c][c];
  }
  #pragma unroll
  for (int c=0; c<64; ++c) Qout[(size_t)c*1024 + col] = z[c];
}

// ---------- 256-thread fp32 64x64 symmetric top-16 eigensolver ----------
// R9 version (readlane broadcasts, dead-chunk skip): proven 151us. I-cache
// theory refuted in R10 (rolled version was SLOWER, 221us); this structure is
// the measured floor across 4 implementations -> serial-chain bound.
__global__ __launch_bounds__(256) void eig16_k(const double* __restrict__ Tin, float* __restrict__ V16){
  __shared__ float A[64][65];          // init staging; reflectors stored in lower columns
  __shared__ float dF[64], eF[64], e2F[64], kapS[64];
  __shared__ float lamF[16];
  __shared__ float IV[5][64][16];      // [0]=L factor f, [1]=recip pivot, [2]=DU, [3]=DU2, [4]=B
  __shared__ float W[16][68];
  int t = threadIdx.x;
  int r = t & 63, p4 = t >> 6;          // row, wave

  for (int e=t; e<4096; e+=256){
    int i = e >> 6, j = e & 63;
    A[i][j] = (float)(0.5*(Tin[i*64+j] + Tin[(size_t)j*64+i]));
  }
  __syncthreads();

  // ---- Householder tridiagonalization: single wave, row-in-registers,
  // readlane broadcasts (no LDS in hot loop), dead-chunk skipping.
  if (p4 == 0){
    float a[64];
    #pragma unroll
    for (int j=0; j<64; ++j) a[j] = A[r][j];
    float ck = a[0];                    // current column-k values (unmasked)
    #pragma unroll 1
    for (int k=0; k<62; ++k){
      int kp1 = k + 1;
      int jb0 = k >> 4;                 // first live 16-chunk
      bool below = (r > k);
      float ckm = below ? ck : 0.f;
      float sig = wred64(ckm*ckm);
      float x1 = lanebc(ck, kp1);
      float rr = sqrtf(sig);
      float alpha = (x1 >= 0.f) ? -rr : rr;
      float kappa = sig - alpha*x1;
      float kinv = (kappa > 1e-30f) ? 1.f/kappa : 0.f;
      float v = ckm;
      if (r == kp1) v = x1 - alpha;
      if (kinv == 0.f) v = 0.f;
      if (r == 0){ eF[k] = (kinv==0.f) ? 0.f : alpha; kapS[k] = (kinv==0.f) ? 0.f : kappa; }
      if (r == k) dF[k] = ck;           // diagonal is final before elimination k
      if (below) A[r][k] = v;           // reflector storage for back-transform
      float pf = 0.f;
      #pragma unroll
      for (int jb=0; jb<4; ++jb){
        if (jb >= jb0){                 // uniform branch
          #pragma unroll
          for (int jj=0; jj<16; ++jj){
            int j = jb*16 + jj;         // compile-time register index
            pf += a[j]*lanebc(v, j);
          }
        }
      }
      float pi = below ? pf*kinv : 0.f;
      float vp = wred64(v*pi);
      float Kc = vp*0.5f*kinv;
      float q = below ? (pi - Kc*v) : 0.f;
      float ckn = 0.f;
      #pragma unroll
      for (int jb=0; jb<4; ++jb){
        if (jb >= jb0){
          #pragma unroll
          for (int jj=0; jj<16; ++jj){
            int j = jb*16 + jj;
            float vj = lanebc(v, j);
            float qj = lanebc(q, j);
            float an = a[j] - (v*qj + q*vj);
            a[j] = an;
            ckn = (j == kp1) ? an : ckn;
          }
        }
      }
      ck = ckn;                         // next column (valid for all lanes)
    }
    if (r == 62) dF[62] = ck;           // ck now holds column 62
    if (r == 63){ eF[62] = ck; dF[63] = a[63]; }
    if (r == 0){ eF[63] = 0.f; kapS[62] = 0.f; kapS[63] = 0.f; }
  }
  __syncthreads();
  if (t < 64) e2F[t] = eF[t]*eF[t];
  __syncthreads();

  // ---- Gershgorin bounds (redundant per wave) ----
  float em1 = (r > 0) ? fabsf(eF[r-1]) : 0.f;
  float ep  = fabsf(eF[r]);
  float glo = wminf(dF[r] - em1 - ep);
  float ghi = wmaxf(dF[r] + em1 + ep);
  float span = ghi - glo + 1.f;
  float lo = glo - 0.001f*span, hi = ghi + 0.001f*span;

  // ---- Sturm 16-point multisection: group (t>>4) owns eigen index 48+(t>>4)
  int eidx = t >> 4, g = t & 15;
  int m = 48 + eidx;
  for (int it=0; it<7; ++it){
    float x = lo + (hi - lo)*((float)(g+1)*(1.0f/17.0f));
    float qq = dF[0] - x;
    int c = (qq < 0.f) ? 1 : 0;
    #pragma unroll
    for (int j=1; j<64; ++j){
      float aq = fabsf(qq);
      float qs = (aq < 1e-10f) ? ((qq < 0.f) ? -1e-10f : 1e-10f) : qq;
      qq = dF[j] - x - e2F[j-1]*__builtin_amdgcn_rcpf(qs);
      c += (qq < 0.f) ? 1 : 0;
    }
    float cl = (c <= m) ? x : -3.4e38f;
    float ch = (c >  m) ? x :  3.4e38f;
    #pragma unroll
    for (int off=1; off<16; off<<=1){
      cl = fmaxf(cl, __shfl_xor(cl, off, 64));
      ch = fminf(ch, __shfl_xor(ch, off, 64));
    }
    lo = fmaxf(lo, cl);
    hi = fminf(hi, ch);
  }
  if (g == 0) lamF[eidx] = 0.5f*(lo + hi);
  __syncthreads();

  // ---- inverse iteration (lanes 0..15): LU + 2 solves, register-rolling
  if (t < 16){
    float lam = lamF[t];
    const float PIVF = 1e-6f;
    #pragma unroll 4
    for (int i=0; i<64; ++i){
      unsigned hsh = (unsigned)(i*131 + t*1009 + 7);
      hsh ^= hsh >> 13; hsh *= 2654435761u; hsh ^= hsh >> 16;
      IV[4][i][t] = (float)(hsh & 0xFFFF) * (1.5f/65536.0f) + 0.25f;
    }
    unsigned long long piv = 0ull;
    float dcur = dF[0] - lam;
    float ducur = eF[0];
    for (int i=0; i<63; ++i){
      float dli = eF[i];
      float dnext = dF[i+1] - lam;
      float eip1 = (i < 62) ? eF[i+1] : 0.f;
      bool sw = fabsf(dcur) < fabsf(dli);
      float dd = dcur;
      if (fabsf(dd) < PIVF) dd = (dd < 0.f) ? -PIVF : PIVF;
      float f = sw ? (dcur*__builtin_amdgcn_rcpf(dli)) : (dli*__builtin_amdgcn_rcpf(dd));
      float ddst = sw ? dli : dd;
      float dust = sw ? dnext : ducur;
      float du2  = sw ? eip1 : 0.f;
      float dnew = sw ? (ducur - f*dnext) : (dnext - f*ducur);
      float dunew= sw ? (-f*eip1) : eip1;
      if (sw) piv |= (1ull << i);
      IV[0][i][t] = f;
      float dc = ddst; if (fabsf(dc) < PIVF) dc = (dc < 0.f) ? -PIVF : PIVF;
      IV[1][i][t] = __builtin_amdgcn_rcpf(dc);
      IV[2][i][t] = dust;
      IV[3][i][t] = du2;
      dcur = dnew; ducur = dunew;
    }
    { float dc = dcur; if (fabsf(dc) < PIVF) dc = (dc < 0.f) ? -PIVF : PIVF; IV[1][63][t] = __builtin_amdgcn_rcpf(dc); }
    float ss = 0.f;
    #pragma unroll 1
    for (int iter=0; iter<2; ++iter){
      float scale = (iter == 0) ? 1.f : rsqrtf(fmaxf(ss, 1e-30f));
      float b = IV[4][0][t]*scale;
      #pragma unroll 7
      for (int i=0; i<63; ++i){
        float bn = IV[4][i+1][t]*scale;
        float f = IV[0][i][t];
        bool sw = (piv >> i) & 1ull;
        float keep = sw ? bn : b;
        float bnew = (sw ? b : bn) - f*keep;
        IV[4][i][t] = keep;
        b = bnew;
      }
      ss = 0.f;
      float x1v = b * IV[1][63][t];
      IV[4][63][t] = x1v; ss += x1v*x1v;
      float x0v = (IV[4][62][t] - IV[2][62][t]*x1v) * IV[1][62][t];
      IV[4][62][t] = x0v; ss += x0v*x0v;
      float xp1 = x0v, xp2 = x1v;
      #pragma unroll 7
      for (int i=61; i>=0; --i){
        float xi = (IV[4][i][t] - IV[2][i][t]*xp1 - IV[3][i][t]*xp2) * IV[1][i][t];
        IV[4][i][t] = xi; ss += xi*xi;
        xp2 = xp1; xp1 = xi;
      }
    }
    #pragma unroll 4
    for (int i=0; i<64; ++i) W[t][i] = IV[4][i][t];   // MGS normalizes
  }
  __syncthreads();

  // ---- MGS re-orth: wave 0 computes/writes, all threads hit barriers ----
  for (int c=0; c<16; ++c){
    float wi = (t < 64) ? W[c][t] : 0.f;
    float s2 = wred64(wi*wi);
    float rn = rsqrtf(fmaxf(s2, 1e-30f));
    wi *= rn;
    if (t < 64) W[c][t] = wi;
    __syncthreads();
    for (int c2=c+1; c2<16; ++c2){
      float w2 = (t < 64) ? W[c2][t] : 0.f;
      float d2 = wred64(wi*w2);
      if (t < 64) W[c2][t] -= d2*wi;
    }
    __syncthreads();
  }

  // ---- back-transform: 4 vecs/wave, 16 lanes/vec, no barriers needed ----
  int cL = (p4 << 2) + (r >> 4);        // eigvec index 0..15
  int part = r & 15;                    // 16 parts x 4 elements
  for (int k=61; k>=0; --k){
    float kpd = kapS[k];
    if (kpd == 0.f) continue;           // wave-uniform
    float invk = 1.f/kpd;
    float vv[4];
    float ps = 0.f;
    #pragma unroll
    for (int mm=0; mm<4; ++mm){
      int i = part*4 + mm;
      vv[mm] = (i > k) ? A[i][k] : 0.f;
      ps += vv[mm]*W[cL][i];
    }
    ps += __shfl_xor(ps, 1, 64);
    ps += __shfl_xor(ps, 2, 64);
    ps += __shfl_xor(ps, 4, 64);
    ps += __shfl_xor(ps, 8, 64);
    float sc = ps * invk;
    #pragma unroll
    for (int mm=0; mm<4; ++mm){
      int i = part*4 + mm;
      W[cL][i] -= vv[mm]*sc;
    }
  }
  __syncthreads();

  for (int e=t; e<1024; e+=256){
    int j = e >> 4, c = e & 15;
    V16[e] = W[c][j];
  }
}

__global__ __launch_bounds__(256) void buildUt_k(const float* __restrict__ V16,
                                                 const float* __restrict__ Qt, float* __restrict__ Ut, float* __restrict__ UtT){
  int bx = blockIdx.x;
  int c = bx & 15, kc = bx >> 4;
  int k = kc*256 + threadIdx.x;
  float acc = 0.f;
  #pragma unroll
  for (int j=0; j<64; ++j) acc += V16[j*16 + c] * Qt[(size_t)j*1024 + k];
  Ut[(size_t)c*1024 + k] = acc;
  UtT[(size_t)k*16 + c] = acc;
}

__global__ void s16_k(const float* __restrict__ cs, const float* __restrict__ Ut, float* __restrict__ s16){
  __shared__ float red[16][17];
  int t = threadIdx.x;
  int c = t & 15, part = t >> 4;
  float acc = 0.f;
  for (int d=0; d<64; ++d) acc += cs[part*64 + d] * Ut[(size_t)c*1024 + part*64 + d];
  red[c][part] = acc;
  __syncthreads();
  if (t < 16){
    float s = 0.f;
    #pragma unroll
    for (int p2=0; p2<16; ++p2) s += red[t][p2];
    s16[t] = s * (1.0f/16384.0f);
  }
}

__global__ __launch_bounds__(256) void proj_k(const float* __restrict__ X, const float* __restrict__ UtT,
                                              const float* __restrict__ s16, float* __restrict__ F){
  int r0 = blockIdx.x * 64;
  int t = threadIdx.x;
  __shared__ __attribute__((aligned(16))) float uts[16384];   // [1024][16]
  #pragma unroll
  for (int w=0; w<16; ++w)
    ((float4*)uts)[t + 256*w] = ((const float4*)UtT)[t + 256*w];
  __syncthreads();
  int row = t & 63, kp = t >> 6;
  const float* xr = X + (size_t)(r0 + row)*1024 + kp*256;
  const float* ut = uts + kp*256*16;
  float acc[16];
  #pragma unroll
  for (int c=0;c<16;++c) acc[c] = 0.f;
  for (int dd=0; dd<256; dd+=4){
    float4 xv4 = *(const float4*)(xr + dd);
    float xv[4] = {xv4.x, xv4.y, xv4.z, xv4.w};
    #pragma unroll
    for (int u=0; u<4; ++u)
      #pragma unroll
      for (int c=0;c<16;++c) acc[c] += xv[u] * ut[(dd+u)*16 + c];
  }
  __shared__ float part[4][64][16];
  #pragma unroll
  for (int c=0;c<16;++c) part[kp][row][c] = acc[c];
  __syncthreads();
  int cq = t >> 6;
  #pragma unroll
  for (int ccx=0; ccx<4; ++ccx){
    int c = cq*4 + ccx;
    float v = part[0][row][c] + part[1][row][c] + part[2][row][c] + part[3][row][c] - s16[c];
    F[(size_t)(r0 + row)*16 + c] = v;
  }
}

__global__ __launch_bounds__(256) void stats_k(const float* __restrict__ F, const int* __restrict__ lbl, float* __restrict__ SG){
  __shared__ float st[10][154];
  int t = threadIdx.x;
  for (int e=t; e<1540; e+=256) st[e/154][e%154] = 0.f;
  __syncthreads();
  int r = blockIdx.x*256 + t;
  float f[16];
  #pragma unroll
  for (int w=0; w<4; ++w){
    float4 v = *(const float4*)(F + (size_t)r*16 + w*4);
    f[w*4+0]=v.x; f[w*4+1]=v.y; f[w*4+2]=v.z; f[w*4+3]=v.w;
  }
  int c = lbl[r];
  if ((unsigned)c < 10u){
    float* bs = &st[c][0];
    atomicAdd(&bs[0], 1.f);
    #pragma unroll
    for (int a=0;a<16;++a) atomicAdd(&bs[1+a], f[a]);
    int sidx = 17;
    #pragma unroll
    for (int a=0;a<16;++a)
      #pragma unroll
      for (int b2=a;b2<16;++b2) atomicAdd(&bs[sidx++], f[a]*f[b2]);
  }
  __syncthreads();
  for (int e=t; e<1530; e+=256) atomicAdd(&SG[e], st[e/153][e%153]);
}

__global__ __launch_bounds__(256) void final_k(const float* __restrict__ SG, float* __restrict__ out){
  __shared__ double cnt[10], safe[10], ldet[10];
  __shared__ double mean[10][16];
  __shared__ double Sig[10][16][16];
  __shared__ double Inv[10][16][16];
  __shared__ double red[128];
  int t = threadIdx.x;
  if (t < 10){
    double c0 = (double)SG[t*153];
    cnt[t] = c0; safe[t] = (c0 > 0.0) ? c0 : 1.0;
  }
  __syncthreads();
  for (int e=t; e<160; e+=256){
    int c = e >> 4, a = e & 15;
    mean[c][a] = (double)SG[c*153 + 1 + a] / safe[c];
  }
  __syncthreads();
  for (int e=t; e<2560; e+=256){
    int c = e >> 8, ab = e & 255, a = ab >> 4, b2 = ab & 15;
    int lo = a < b2 ? a : b2, hi = a < b2 ? b2 : a;
    int ti = lo*(33 - lo)/2 + (hi - lo);
    Sig[c][a][b2] = (double)SG[c*153 + 17 + ti]/safe[c] - mean[c][a]*mean[c][b2] + ((a==b2)?1.0:0.0);
  }
  __syncthreads();
  if (t < 10){
    for (int a=0;a<16;++a)
      for (int b2=0;b2<16;++b2) Inv[t][a][b2] = Sig[t][a][b2];
    double ld2 = 0.0;
    for (int k=0;k<16;++k){
      double v = Inv[t][k][k];
      for (int j=0;j<k;++j) v -= Inv[t][k][j]*Inv[t][k][j];
      v = fmax(v, 1e-280);
      double lkk = sqrt(v);
      Inv[t][k][k] = lkk; ld2 += log(lkk);
      for (int i=k+1;i<16;++i){
        double w = Inv[t][i][k];
        for (int j=0;j<k;++j) w -= Inv[t][i][j]*Inv[t][k][j];
        Inv[t][i][k] = w / lkk;
      }
    }
    ldet[t] = 2.0*ld2;
    for (int j=0;j<16;++j){
      double dj = 1.0 / Inv[t][j][j];
      Inv[t][j][j] = dj;
      for (int i=j+1;i<16;++i){
        double ssum = Inv[t][i][j]*dj;
        for (int k=j+1;k<i;++k) ssum += Inv[t][i][k]*Inv[t][k][j];
        Inv[t][i][j] = -ssum / Inv[t][i][i];
      }
    }
    double dg[16];
    #pragma unroll
    for (int a=0;a<16;++a){
      double s2 = 0.0;
      for (int k=a;k<16;++k){ double x = Inv[t][k][a]; s2 += x*x; }
      dg[a] = s2;
    }
    for (int a=0;a<16;++a)
      for (int b2=a+1;b2<16;++b2){
        double s2 = 0.0;
        for (int k=b2;k<16;++k) s2 += Inv[t][k][a]*Inv[t][k][b2];
        Inv[t][a][b2] = s2;
      }
    for (int a=0;a<16;++a) Inv[t][a][a] = dg[a];
    for (int a=0;a<16;++a)
      for (int b2=a+1;b2<16;++b2) Inv[t][b2][a] = Inv[t][a][b2];
  }
  __syncthreads();
  double contrib = 0.0;
  if (t < 100){
    int i = t/10, j = t%10;
    if (i != j && cnt[i] > 0.0 && cnt[j] > 0.0){
      double tr = 0.0;
      for (int a=0;a<16;++a)
        for (int b2=0;b2<16;++b2) tr += Inv[j][a][b2]*Sig[i][b2][a];
      double dm[16];
      #pragma unroll
      for (int a=0;a<16;++a) dm[a] = mean[j][a] - mean[i][a];
      double mah = 0.0;
      for (int a=0;a<16;++a){
        double rs = 0.0;
        for (int b2=0;b2<16;++b2) rs += Inv[j][a][b2]*dm[b2];
        mah += dm[a]*rs;
      }
      double kl = 0.5*(tr + mah - 16.0 + ldet[j] - ldet[i]);
      contrib = kl * cnt[i]*cnt[j];
    }
  }
  if (t < 128) red[t] = contrib;
  __syncthreads();
  for (int off=64; off>0; off >>= 1){
    if (t < off) red[t] += red[t+off];
    __syncthreads();
  }
  if (t == 0) out[0] = (float)(red[0] / (16384.0*16384.0*16384.0));
}

// ---------------- host ----------------
extern "C" void kernel_launch(void* const* d_in, const int* in_sizes, int n_in,
                              void* d_out, int out_size, void* d_ws, size_t ws_size,
                              hipStream_t stream){
  (void)in_sizes; (void)n_in; (void)out_size; (void)ws_size;
  const float* X  = (const float*)d_in[0];
  const int* lbl  = (const int*)d_in[1];
  char* ws = (char*)d_ws;
  float*  C    = (float*)(ws + OFF_C);     // Gram -> Chat -> M4
  float*  Mm   = (float*)(ws + OFF_M);     // M  = T2(Chat)
  float*  P    = (float*)(ws + OFF_P);     // M2 = T4(Chat), then mv partials
  float*  Y0   = (float*)(ws + OFF_Y0);
  float*  Y1   = (float*)(ws + OFF_Y1);
  float*  Y2   = (float*)(ws + OFF_Y2);
  float*  Y3   = (float*)(ws + OFF_Y3);
  float*  CQ   = (float*)(ws + OFF_CQ);
  double* S64  = (double*)(ws + OFF_S64);
  double* T64  = (double*)(ws + OFF_T64);
  float*  V16  = (float*)(ws + OFF_V16);
  float*  UT   = (float*)(ws + OFF_UT);
  float*  UTT  = (float*)(ws + OFF_UTT);
  float*  S16  = (float*)(ws + OFF_S16);
  float*  CS   = (float*)(ws + OFF_CS);
  float*  SCAL = (float*)(ws + OFF_SCAL);
  float*  STAT = (float*)(ws + OFF_STAT);
  float*  F    = (float*)(ws + OFF_F);
  float*  OUT  = (float*)d_out;

  hipMemsetAsync(C, 0, 4*1024*1024, stream);
  hipMemsetAsync(ws + OFF_CS, 0, 12800, stream);   // CS + TR + SCAL + STAT

  colsum_k<<<256, 256, 0, stream>>>(X, CS);
  syrk_mfma_k<<<36*SYRK_SLICES, 256, 0, stream>>>(X, C);
  trace_k<<<1, 256, 0, stream>>>(C, CS, SCAL);
  formCChat_k<<<4096, 256, 0, stream>>>(C, CS, SCAL);  // C := Chat
  syrkT2_k<<<36, 256, 0, stream>>>(C, Mm);             // Mm = T2(Chat) (fused formM)
  syrkT2_k<<<36, 256, 0, stream>>>(Mm, P);             // P  = T4(Chat)
  syrkT2_k<<<36, 256, 0, stream>>>(P, C);              // C  = T8(Chat)  (M4)
  rng_k<<<256, 256, 0, stream>>>(Y0);

  // stage filter: T16(Chat)U = T2(M4)U = 2*M4*(M4*U) - U  (2 mv+combine pairs)
  auto cheb2 = [&](float* U, float* Wb, float* Ob){
    mv_k<<<256, 256, 0, stream>>>(U, C, P);
    combine_k<<<64, 256, 0, stream>>>(P, U, Wb, 0);          // Wb = M4*U
    mv_k<<<256, 256, 0, stream>>>(Wb, C, P);
    combine_k<<<64, 256, 0, stream>>>(P, U, Ob, 1);          // Ob = 2*M4*Wb - U
  };
  auto cholqr = [&](float* Yin, float* Qout){
    gram_k<<<256, 256, 0, stream>>>(Yin, Yin, S64);
    cholsolve_k<<<4, 256, 0, stream>>>(S64, Yin, Qout);
  };

  // stage 1: filter random block, single CholQR (conditioning only)
  cheb2(Y0, Y1, Y2);
  cholqr(Y2, Y0);                      // Q1 = Y0
  // stage 2 + CholQR2 (full orthonormality before RR)
  cheb2(Y0, Y1, Y2);
  cholqr(Y2, Y1);
  cholqr(Y1, Y3);                      // Qf = Y3

  // Rayleigh-Ritz in M-space: T = Q^T M Q
  mv_k<<<256, 256, 0, stream>>>(Y3, Mm, P);
  combine_k<<<64, 256, 0, stream>>>(P, Y3, CQ, 0);     // CQ = M Q
  gram_k<<<256, 256, 0, stream>>>(Y3, CQ, T64);
  eig16_k<<<1, 256, 0, stream>>>(T64, V16);
  buildUt_k<<<64, 256, 0, stream>>>(V16, Y3, UT, UTT);

  // project and GMM loss
  s16_k<<<1, 256, 0, stream>>>(CS, UT, S16);
  proj_k<<<256, 256, 0, stream>>>(X, UTT, S16, F);
  stats_k<<<64, 256, 0, stream>>>(F, lbl, STAT);
  final_k<<<1, 256, 0, stream>>>(STAT, OUT);
}